// Round 1
// baseline (960.661 us; speedup 1.0000x reference)
//
#include <hip/hip_runtime.h>
#include <hip/hip_bf16.h>
#include <math.h>

#define Bdim 16
#define Mdim 4096
#define Tdim 4
#define Ddim 256
#define Vdim 40000
#define CONVMAX 512

// ---------------------------------------------------------------------------
// Emb[k][b,m,:] = sum_t C_emb[k][story[b,m,t],:]  (+ history LM window)
// grid: 4 * B * (M/4) blocks, 256 threads (wave per m, lane holds float4)
// ---------------------------------------------------------------------------
__global__ void embed_kernel(const int* __restrict__ story, const int* __restrict__ kb_len,
                             const int* __restrict__ conv_len, const float* __restrict__ hist,
                             const float* __restrict__ C_emb,
                             float* __restrict__ e0, float* __restrict__ e1,
                             float* __restrict__ e2, float* __restrict__ e3) {
    int bid = blockIdx.x;
    int k   = bid / (Bdim * (Mdim / 4));
    int rem = bid % (Bdim * (Mdim / 4));
    int b   = rem / (Mdim / 4);
    int mc  = rem % (Mdim / 4);
    int tid = threadIdx.x;
    int mi  = tid >> 6;
    int lane = tid & 63;
    int m   = mc * 4 + mi;
    int d4  = lane * 4;

    const int* st = story + ((size_t)b * Mdim + m) * Tdim;
    const float* tab = C_emb + (size_t)k * Vdim * Ddim;
    float4 acc = make_float4(0.f, 0.f, 0.f, 0.f);
#pragma unroll
    for (int t = 0; t < Tdim; ++t) {
        int row = st[t];
        const float4 v = *(const float4*)(tab + (size_t)row * Ddim + d4);
        acc.x += v.x; acc.y += v.y; acc.z += v.z; acc.w += v.w;
    }
    int kb = kb_len[b], cl = conv_len[b];
    if (m >= kb && m < kb + cl) {
        const float4 h = *(const float4*)(hist + ((size_t)b * CONVMAX + (m - kb)) * Ddim + d4);
        acc.x += h.x; acc.y += h.y; acc.z += h.z; acc.w += h.w;
    }
    float* outp = (k == 0) ? e0 : (k == 1) ? e1 : (k == 2) ? e2 : e3;
    *(float4*)(outp + ((size_t)b * Mdim + m) * Ddim + d4) = acc;
}

// ---------------------------------------------------------------------------
// logits[b,m] = dot(emb[b,m,:], u[b,:])   (* gp[b,m] if gp != nullptr)
// grid: B*M/4 blocks, 256 threads (wave per m)
// ---------------------------------------------------------------------------
__global__ void logit_kernel(const float* __restrict__ emb, const float* __restrict__ u,
                             const float* __restrict__ gp, float* __restrict__ logits) {
    int tid = threadIdx.x;
    int mi = tid >> 6, lane = tid & 63;
    int row = blockIdx.x * 4 + mi;             // [0, B*M)
    int b = row >> 12;                         // row / M
    const float4 e  = *(const float4*)(emb + (size_t)row * Ddim + lane * 4);
    const float4 uv = *(const float4*)(u + (size_t)b * Ddim + lane * 4);
    float p = e.x * uv.x + e.y * uv.y + e.z * uv.z + e.w * uv.w;
#pragma unroll
    for (int off = 32; off > 0; off >>= 1) p += __shfl_xor(p, off, 64);
    if (lane == 0) {
        if (gp) p *= gp[row];
        logits[row] = p;
    }
}

// ---------------------------------------------------------------------------
// per-batch softmax stats (max, 1/sumexp); optionally zero the o accumulator
// grid: B blocks, 256 threads
// ---------------------------------------------------------------------------
__global__ void stats_kernel(const float* __restrict__ logits, float* __restrict__ maxv,
                             float* __restrict__ rsum, float* __restrict__ o_zero) {
    int b = blockIdx.x, tid = threadIdx.x;
    __shared__ float sh[256];
    const float* lg = logits + (size_t)b * Mdim;
    if (o_zero) o_zero[(size_t)b * Ddim + tid] = 0.f;
    float mx = -INFINITY;
    for (int i = tid; i < Mdim; i += 256) mx = fmaxf(mx, lg[i]);
    sh[tid] = mx; __syncthreads();
    for (int s = 128; s > 0; s >>= 1) { if (tid < s) sh[tid] = fmaxf(sh[tid], sh[tid + s]); __syncthreads(); }
    float bm = sh[0]; __syncthreads();
    float sm = 0.f;
    for (int i = tid; i < Mdim; i += 256) sm += expf(lg[i] - bm);
    sh[tid] = sm; __syncthreads();
    for (int s = 128; s > 0; s >>= 1) { if (tid < s) sh[tid] += sh[tid + s]; __syncthreads(); }
    if (tid == 0) { maxv[b] = bm; rsum[b] = 1.0f / sh[0]; }
}

// ---------------------------------------------------------------------------
// acc_out[b,:] += sum_m prob[b,m] (*gp) * embC[b,m,:]   over a 128-row m-tile
// grid: B * (M/128) blocks, 256 threads (thread = one d element)
// ---------------------------------------------------------------------------
#define MT 128
__global__ void attend_kernel(const float* __restrict__ embC, const float* __restrict__ logits,
                              const float* __restrict__ maxv, const float* __restrict__ rsum,
                              const float* __restrict__ gp, float* __restrict__ acc_out) {
    int bid = blockIdx.x;
    int b  = bid / (Mdim / MT);
    int m0 = (bid % (Mdim / MT)) * MT;
    int tid = threadIdx.x;
    __shared__ float prob[MT];
    if (tid < MT) {
        int row = b * Mdim + m0 + tid;
        float p = expf(logits[row] - maxv[b]) * rsum[b];
        if (gp) p *= gp[row];
        prob[tid] = p;
    }
    __syncthreads();
    float acc = 0.f;
    const float* base = embC + ((size_t)b * Mdim + m0) * Ddim + tid;
#pragma unroll 4
    for (int mm = 0; mm < MT; ++mm) acc += prob[mm] * base[(size_t)mm * Ddim];
    atomicAdd(&acc_out[(size_t)b * Ddim + tid], acc);
}

// ---------------------------------------------------------------------------
// cur_u[0] = iq  (layer 0: copy q; layer>0: gated merge with prev_u[0])
// grid: B blocks, 256 threads
// ---------------------------------------------------------------------------
__global__ void layer_start_kernel(int use_gate, const float* __restrict__ q,
                                   const float* __restrict__ W0, const float* __restrict__ b0,
                                   const float* __restrict__ prevu0, float* __restrict__ u0) {
    int b = blockIdx.x, i = threadIdx.x;
    float qi = q[(size_t)b * Ddim + i];
    if (!use_gate) { u0[(size_t)b * Ddim + i] = qi; return; }
    __shared__ float sh[Ddim];
    sh[i] = qi; __syncthreads();
    float s = b0[i];
    for (int j = 0; j < Ddim; ++j) s += W0[(size_t)i * Ddim + j] * sh[j];
    float g = 1.0f / (1.0f + expf(-s));
    u0[(size_t)b * Ddim + i] = prevu0[(size_t)b * Ddim + i] * g + qi * (1.0f - g);
}

// ---------------------------------------------------------------------------
// u_out = (u_in + o), optionally gated with prev layer's u[hop+1]
// grid: B blocks, 256 threads
// ---------------------------------------------------------------------------
__global__ void u_update_kernel(const float* __restrict__ u_in, const float* __restrict__ o,
                                int use_gate, const float* __restrict__ W, const float* __restrict__ bias,
                                const float* __restrict__ prevu, float* __restrict__ u_out) {
    int b = blockIdx.x, i = threadIdx.x;
    float uk = u_in[(size_t)b * Ddim + i] + o[(size_t)b * Ddim + i];
    if (!use_gate) { u_out[(size_t)b * Ddim + i] = uk; return; }
    __shared__ float sh[Ddim];
    sh[i] = uk; __syncthreads();
    float s = bias[i];
    for (int j = 0; j < Ddim; ++j) s += W[(size_t)i * Ddim + j] * sh[j];
    float g = 1.0f / (1.0f + expf(-s));
    u_out[(size_t)b * Ddim + i] = prevu[(size_t)b * Ddim + i] * g + uk * (1.0f - g);
}

// ---------------------------------------------------------------------------
// q = relu(u3 @ FW_w.T + FW_b)   grid: B blocks, 256 threads
// ---------------------------------------------------------------------------
__global__ void layer_end_kernel(const float* __restrict__ u3, const float* __restrict__ W,
                                 const float* __restrict__ bias, float* __restrict__ qout) {
    int b = blockIdx.x, i = threadIdx.x;
    __shared__ float sh[Ddim];
    sh[i] = u3[(size_t)b * Ddim + i]; __syncthreads();
    float s = bias[i];
    for (int j = 0; j < Ddim; ++j) s += W[(size_t)i * Ddim + j] * sh[j];
    qout[(size_t)b * Ddim + i] = fmaxf(s, 0.f);
}

__global__ void copy_kernel(const float* __restrict__ src, float* __restrict__ dst) {
    int b = blockIdx.x, i = threadIdx.x;
    dst[(size_t)b * Ddim + i] = src[(size_t)b * Ddim + i];
}

// psoft[b,m] = exp(logits[b,m]-max)/sum  grid: B*M/256 blocks, 256 threads
__global__ void psoft_kernel(const float* __restrict__ logits, const float* __restrict__ maxv,
                             const float* __restrict__ rsum, float* __restrict__ psoft) {
    int row = blockIdx.x * 256 + threadIdx.x;
    int b = row >> 12;
    psoft[row] = expf(logits[row] - maxv[b]) * rsum[b];
}

extern "C" void kernel_launch(void* const* d_in, const int* in_sizes, int n_in,
                              void* d_out, int out_size, void* d_ws, size_t ws_size,
                              hipStream_t stream) {
    const int*   story        = (const int*)d_in[0];
    const int*   kb_len       = (const int*)d_in[1];
    const int*   conv_len     = (const int*)d_in[2];
    const float* query        = (const float*)d_in[3];
    const float* hist         = (const float*)d_in[4];
    const float* query_vector = (const float*)d_in[5];
    const float* gp           = (const float*)d_in[6];
    const float* C_emb        = (const float*)d_in[7];
    const float* Tg_w         = (const float*)d_in[8];
    const float* Tg_b         = (const float*)d_in[9];
    const float* FW_w         = (const float*)d_in[10];
    const float* FW_b         = (const float*)d_in[11];

    float* out        = (float*)d_out;
    float* out_psoft  = out;                                   // B*M
    float* out_logits = out + (size_t)Bdim * Mdim;             // B*M
    float* out_uf     = out + 2 * (size_t)Bdim * Mdim;         // B*D
    float* out_m      = out + 2 * (size_t)Bdim * Mdim + (size_t)Bdim * Ddim; // B*M*D

    const size_t EMB = (size_t)Bdim * Mdim * Ddim;
    float* ws = (float*)d_ws;
    float* emb[4];
    emb[0] = ws;
    emb[1] = ws + EMB;
    emb[2] = ws + 2 * EMB;
    emb[3] = out_m;
    float* logits = ws + 3 * EMB;                 // B*M
    float* maxv   = logits + (size_t)Bdim * Mdim; // B
    float* rsum   = maxv + Bdim;                  // B
    float* o      = rsum + Bdim;                  // B*D
    float* uA     = o + (size_t)Bdim * Ddim;      // 4*B*D
    float* uB     = uA + 4 * (size_t)Bdim * Ddim; // 4*B*D
    float* qbuf   = uB + 4 * (size_t)Bdim * Ddim; // B*D

    embed_kernel<<<4 * Bdim * (Mdim / 4), 256, 0, stream>>>(
        story, kb_len, conv_len, hist, C_emb, emb[0], emb[1], emb[2], emb[3]);

    float* cur = uA;
    float* prev = uB;
    for (int layer = 0; layer < 3; ++layer) {
        layer_start_kernel<<<Bdim, Ddim, 0, stream>>>(
            layer > 0, (layer == 0) ? query : qbuf, Tg_w, Tg_b, prev, cur);
        for (int hop = 0; hop < 3; ++hop) {
            logit_kernel<<<Bdim * Mdim / 4, 256, 0, stream>>>(
                emb[hop], cur + (size_t)hop * Bdim * Ddim, nullptr, logits);
            stats_kernel<<<Bdim, 256, 0, stream>>>(logits, maxv, rsum, o);
            attend_kernel<<<Bdim * (Mdim / MT), 256, 0, stream>>>(
                emb[hop + 1], logits, maxv, rsum, nullptr, o);
            u_update_kernel<<<Bdim, Ddim, 0, stream>>>(
                cur + (size_t)hop * Bdim * Ddim, o, layer > 0,
                Tg_w + (size_t)(hop + 1) * Ddim * Ddim, Tg_b + (size_t)(hop + 1) * Ddim,
                prev + (size_t)(hop + 1) * Bdim * Ddim, cur + (size_t)(hop + 1) * Bdim * Ddim);
        }
        layer_end_kernel<<<Bdim, Ddim, 0, stream>>>(cur + 3 * (size_t)Bdim * Ddim, FW_w, FW_b, qbuf);
        float* tmp = cur; cur = prev; prev = tmp;
    }

    // final global-pointer stage
    copy_kernel<<<Bdim, Ddim, 0, stream>>>(query_vector, out_uf);
    for (int h = 0; h < 3; ++h) {
        float* lg = (h == 2) ? out_logits : logits;
        logit_kernel<<<Bdim * Mdim / 4, 256, 0, stream>>>(emb[h], out_uf, gp, lg);
        stats_kernel<<<Bdim, 256, 0, stream>>>(lg, maxv, rsum, nullptr);
        attend_kernel<<<Bdim * (Mdim / MT), 256, 0, stream>>>(emb[h + 1], lg, maxv, rsum, gp, out_uf);
        if (h == 2)
            psoft_kernel<<<Bdim * Mdim / 256, 256, 0, stream>>>(lg, maxv, rsum, out_psoft);
    }
}